// Round 1
// baseline (141.838 us; speedup 1.0000x reference)
//
#include <hip/hip_runtime.h>
#include <hip/hip_bf16.h>

#define NROW 8192
#define DDIM 512
#define BM 128
#define BN 128
#define BK 32
#define MARGIN 0.2f

typedef __bf16 bf16x8 __attribute__((ext_vector_type(8)));
typedef float f32x4 __attribute__((ext_vector_type(4)));

__device__ __forceinline__ void gload16(const void* g, void* l) {
    __builtin_amdgcn_global_load_lds(
        (const __attribute__((address_space(1))) void*)g,
        (__attribute__((address_space(3))) void*)l, 16, 0, 0);
}

// ---------------------------------------------------------------------------
// prep: blocks 0..N-1 handle im (convert + ||im||^2 + diag), N..2N-1 handle ex
// ---------------------------------------------------------------------------
__global__ __launch_bounds__(256) void prep_kernel(
    const float* __restrict__ im, const float* __restrict__ s,
    const float* __restrict__ ex,
    ushort* __restrict__ Abf, ushort* __restrict__ Bbf,
    float* __restrict__ imsq, float* __restrict__ exsq,
    float* __restrict__ diag) {
    int b = blockIdx.x;
    bool isim = b < NROW;
    int row = isim ? b : b - NROW;
    const float* src = isim ? im : ex;
    ushort* dst = isim ? Abf : Bbf;

    float ssq = 0.f, dsq = 0.f;
    for (int t = threadIdx.x; t < DDIM; t += 256) {
        size_t idx = (size_t)row * DDIM + t;
        float v = src[idx];
        __hip_bfloat16 h = __float2bfloat16(v);
        dst[idx] = *(const ushort*)&h;
        ssq += v * v;
        if (isim) { float d = v - s[idx]; dsq += d * d; }
    }
    #pragma unroll
    for (int off = 32; off > 0; off >>= 1) {
        ssq += __shfl_down(ssq, off);
        dsq += __shfl_down(dsq, off);
    }
    __shared__ float sred[8];
    int lane = threadIdx.x & 63, w = threadIdx.x >> 6;
    if (lane == 0) { sred[w] = ssq; sred[4 + w] = dsq; }
    __syncthreads();
    if (threadIdx.x == 0) {
        float S = sred[0] + sred[1] + sred[2] + sred[3];
        float Dd = sred[4] + sred[5] + sred[6] + sred[7];
        if (isim) { imsq[row] = S; diag[row] = -sqrtf(Dd); }
        else      { exsq[row] = S; }
    }
}

// ---------------------------------------------------------------------------
// GEMM + fused epilogue. C = im_bf16 @ ex_bf16^T  (both row-major [N][D]).
// 128x128 tile, BK=32, 4 waves each owning a 64x64 quadrant (4x4 16x16 frags).
// Epilogue computes hinge cost per element and block-reduces to partials.
// ---------------------------------------------------------------------------
__global__ __launch_bounds__(256) void gemm_cost_kernel(
    const ushort* __restrict__ Abf, const ushort* __restrict__ Bbf,
    const float* __restrict__ imsq, const float* __restrict__ exsq,
    const float* __restrict__ diag, float* __restrict__ partials) {
    __shared__ __align__(16) ushort sA[BM * BK];  // 8 KB
    __shared__ __align__(16) ushort sB[BN * BK];  // 8 KB

    int bid = blockIdx.x;
    int bi = bid >> 6;       // N/BN = 64 tiles per row
    int bj = bid & 63;
    int ibase = bi * BM;
    int jbase = bj * BN;
    int tid = threadIdx.x;
    int lane = tid & 63;
    int w = tid >> 6;        // wave 0..3
    int wr = w >> 1;         // 0..1
    int wc = w & 1;          // 0..1

    f32x4 acc[4][4] = {};

    for (int k0 = 0; k0 < DDIM; k0 += BK) {
        // stage A and B tiles: 8KB each, 512 chunks of 16B, 256 threads x 2 rounds
        #pragma unroll
        for (int t = 0; t < 2; ++t) {
            int c = t * 256 + tid;                 // 0..511
            int r = c >> 2;                        // row in tile 0..127
            int kc = (c & 3) * 8;                  // k offset 0,8,16,24
            const ushort* ga = Abf + (size_t)(ibase + r) * DDIM + k0 + kc;
            gload16(ga, (char*)sA + c * 16);
            const ushort* gb = Bbf + (size_t)(jbase + r) * DDIM + k0 + kc;
            gload16(gb, (char*)sB + c * 16);
        }
        __syncthreads();

        bf16x8 af[4], bfr[4];
        #pragma unroll
        for (int m = 0; m < 4; ++m)
            af[m] = *(const bf16x8*)&sA[(wr * 64 + m * 16 + (lane & 15)) * BK + (lane >> 4) * 8];
        #pragma unroll
        for (int n = 0; n < 4; ++n)
            bfr[n] = *(const bf16x8*)&sB[(wc * 64 + n * 16 + (lane & 15)) * BK + (lane >> 4) * 8];

        #pragma unroll
        for (int m = 0; m < 4; ++m)
            #pragma unroll
            for (int n = 0; n < 4; ++n)
                acc[m][n] = __builtin_amdgcn_mfma_f32_16x16x32_bf16(af[m], bfr[n], acc[m][n], 0, 0, 0);
        __syncthreads();
    }

    // epilogue: cost = max(MARGIN - sqrt(max(imsq[i]+exsq[j]-2*dot,0)) - diag[i], 0)
    // C/D layout (HW-verified): col = lane&15, row = (lane>>4)*4 + reg
    float lsum = 0.f;
    int r0 = (lane >> 4) * 4;
    int cc = lane & 15;
    #pragma unroll
    for (int m = 0; m < 4; ++m) {
        int i0 = ibase + wr * 64 + m * 16 + r0;
        #pragma unroll
        for (int n = 0; n < 4; ++n) {
            int j = jbase + wc * 64 + n * 16 + cc;
            float esq = exsq[j];
            #pragma unroll
            for (int r = 0; r < 4; ++r) {
                int i = i0 + r;
                float d2 = imsq[i] + esq - 2.0f * acc[m][n][r];
                d2 = fmaxf(d2, 0.0f);
                float c = MARGIN - sqrtf(d2) - diag[i];
                lsum += fmaxf(c, 0.0f);
            }
        }
    }
    #pragma unroll
    for (int off = 32; off > 0; off >>= 1) lsum += __shfl_down(lsum, off);
    __shared__ float redbuf[4];
    if (lane == 0) redbuf[w] = lsum;
    __syncthreads();
    if (tid == 0) partials[bid] = redbuf[0] + redbuf[1] + redbuf[2] + redbuf[3];
}

// ---------------------------------------------------------------------------
// deterministic final reduce: 4096 partials -> mean
// ---------------------------------------------------------------------------
__global__ __launch_bounds__(256) void finalize_kernel(
    const float* __restrict__ partials, float* __restrict__ out) {
    float acc = 0.f;
    for (int t = threadIdx.x; t < 4096; t += 256) acc += partials[t];
    #pragma unroll
    for (int off = 32; off > 0; off >>= 1) acc += __shfl_down(acc, off);
    __shared__ float sred[4];
    int lane = threadIdx.x & 63, w = threadIdx.x >> 6;
    if (lane == 0) sred[w] = acc;
    __syncthreads();
    if (threadIdx.x == 0) {
        float total = sred[0] + sred[1] + sred[2] + sred[3];
        out[0] = total * (1.0f / (8192.0f * 8192.0f));  // exact pow2 scale
    }
}

extern "C" void kernel_launch(void* const* d_in, const int* in_sizes, int n_in,
                              void* d_out, int out_size, void* d_ws, size_t ws_size,
                              hipStream_t stream) {
    const float* im = (const float*)d_in[0];
    const float* s  = (const float*)d_in[1];
    const float* ex = (const float*)d_in[2];

    // workspace layout (~16.9 MB)
    char* ws = (char*)d_ws;
    ushort* Abf   = (ushort*)(ws);                       // 8 MB
    ushort* Bbf   = (ushort*)(ws + 8388608);             // 8 MB
    float* imsq   = (float*)(ws + 16777216);             // 32 KB
    float* exsq   = (float*)(ws + 16809984);             // 32 KB
    float* diag   = (float*)(ws + 16842752);             // 32 KB
    float* parts  = (float*)(ws + 16875520);             // 16 KB

    prep_kernel<<<2 * NROW, 256, 0, stream>>>(im, s, ex, Abf, Bbf, imsq, exsq, diag);
    gemm_cost_kernel<<<(NROW / BM) * (NROW / BN), 256, 0, stream>>>(Abf, Bbf, imsq, exsq, diag, parts);
    finalize_kernel<<<1, 256, 0, stream>>>(parts, (float*)d_out);
}

// Round 2
// 141.586 us; speedup vs baseline: 1.0018x; 1.0018x over previous
//
#include <hip/hip_runtime.h>
#include <hip/hip_bf16.h>

#define NROW 8192
#define DDIM 512
#define BM 128
#define BN 128
#define BK 64
#define MARGIN 0.2f

typedef __bf16 bf16x8 __attribute__((ext_vector_type(8)));
typedef float f32x4 __attribute__((ext_vector_type(4)));

__device__ __forceinline__ void gload16(const void* g, void* l) {
    __builtin_amdgcn_global_load_lds(
        (const __attribute__((address_space(1))) void*)g,
        (__attribute__((address_space(3))) void*)l, 16, 0, 0);
}

// ---------------------------------------------------------------------------
// prep: blocks 0..N-1 handle im (convert + ||im||^2 + diag), N..2N-1 handle ex
// 256 threads x float2 = exactly 512 f32 per row.
// ---------------------------------------------------------------------------
__global__ __launch_bounds__(256) void prep_kernel(
    const float* __restrict__ im, const float* __restrict__ s,
    const float* __restrict__ ex,
    ushort* __restrict__ Abf, ushort* __restrict__ Bbf,
    float* __restrict__ imsq, float* __restrict__ exsq,
    float* __restrict__ diag) {
    int b = blockIdx.x;
    bool isim = b < NROW;
    int row = isim ? b : b - NROW;
    const float* src = isim ? im : ex;
    ushort* dst = isim ? Abf : Bbf;
    int tid = threadIdx.x;

    float2 v = ((const float2*)(src + (size_t)row * DDIM))[tid];
    __hip_bfloat16 hx = __float2bfloat16(v.x);
    __hip_bfloat16 hy = __float2bfloat16(v.y);
    unsigned packed = (unsigned)*(const ushort*)&hx | ((unsigned)*(const ushort*)&hy << 16);
    ((unsigned*)(dst + (size_t)row * DDIM))[tid] = packed;

    float ssq = v.x * v.x + v.y * v.y;
    float dsq = 0.f;
    if (isim) {
        float2 sv = ((const float2*)(s + (size_t)row * DDIM))[tid];
        float dx = v.x - sv.x, dy = v.y - sv.y;
        dsq = dx * dx + dy * dy;
    }
    #pragma unroll
    for (int off = 32; off > 0; off >>= 1) {
        ssq += __shfl_down(ssq, off);
        dsq += __shfl_down(dsq, off);
    }
    __shared__ float sred[8];
    int lane = tid & 63, w = tid >> 6;
    if (lane == 0) { sred[w] = ssq; sred[4 + w] = dsq; }
    __syncthreads();
    if (tid == 0) {
        float S = sred[0] + sred[1] + sred[2] + sred[3];
        float Dd = sred[4] + sred[5] + sred[6] + sred[7];
        if (isim) { imsq[row] = S; diag[row] = -sqrtf(Dd); }
        else      { exsq[row] = S; }
    }
}

// ---------------------------------------------------------------------------
// GEMM + fused epilogue. C = im_bf16 @ ex_bf16^T  (both row-major [N][D]).
// 128x128 tile, BK=64, 4 waves each owning a 64x64 quadrant (4x4 16x16 frags).
// LDS layout: [row][64] bf16 (128B rows) with XOR chunk-swizzle
//   physical_chunk = row*8 + (logical_koff ^ (row&7))   (chunk = 16B)
// applied on BOTH sides: pre-swizzled GLOBAL source at staging (LDS dest
// linear, as global_load_lds requires) and swizzled ds_read offset.
// -> 16-lane fragment groups spread over all 8 chunk-classes: 2-way = free.
// ---------------------------------------------------------------------------
__global__ __launch_bounds__(256) void gemm_cost_kernel(
    const ushort* __restrict__ Abf, const ushort* __restrict__ Bbf,
    const float* __restrict__ imsq, const float* __restrict__ exsq,
    const float* __restrict__ diag, float* __restrict__ partials) {
    __shared__ __align__(16) ushort sA[BM * BK];  // 16 KB
    __shared__ __align__(16) ushort sB[BN * BK];  // 16 KB

    // XCD-aware bijective swizzle: nwg = 4096, 4096 % 8 == 0
    int bid0 = blockIdx.x;
    int bid = (bid0 & 7) * 512 + (bid0 >> 3);
    int bi = bid >> 6;       // 64 tiles per row
    int bj = bid & 63;
    int ibase = bi * BM;
    int jbase = bj * BN;
    int tid = threadIdx.x;
    int lane = tid & 63;
    int w = tid >> 6;        // wave 0..3
    int wr = w >> 1;         // 0..1
    int wc = w & 1;          // 0..1

    f32x4 acc[4][4] = {};

    for (int k0 = 0; k0 < DDIM; k0 += BK) {
        // stage: 1024 chunks of 16B per tile; source k pre-swizzled
        #pragma unroll
        for (int t = 0; t < 4; ++t) {
            int c = t * 256 + tid;                     // physical chunk 0..1023
            int r = c >> 3;                            // row in tile
            int kc = ((c ^ (c >> 3)) & 7) * 8;         // swizzled logical k (ushorts)
            gload16(Abf + (size_t)(ibase + r) * DDIM + k0 + kc, (char*)sA + c * 16);
            gload16(Bbf + (size_t)(jbase + r) * DDIM + k0 + kc, (char*)sB + c * 16);
        }
        __syncthreads();

        #pragma unroll
        for (int kk = 0; kk < 2; ++kk) {
            // row&7 == lane&7 for all fragments (row = base16*m + (lane&15))
            int koffb = (((kk << 2) | (lane >> 4)) ^ (lane & 7)) * 16;  // byte offset in row
            bf16x8 af[4], bfr[4];
            #pragma unroll
            for (int m = 0; m < 4; ++m) {
                int row = wr * 64 + m * 16 + (lane & 15);
                af[m] = *(const bf16x8*)((const char*)sA + row * 128 + koffb);
            }
            #pragma unroll
            for (int n = 0; n < 4; ++n) {
                int row = wc * 64 + n * 16 + (lane & 15);
                bfr[n] = *(const bf16x8*)((const char*)sB + row * 128 + koffb);
            }
            #pragma unroll
            for (int m = 0; m < 4; ++m)
                #pragma unroll
                for (int n = 0; n < 4; ++n)
                    acc[m][n] = __builtin_amdgcn_mfma_f32_16x16x32_bf16(af[m], bfr[n], acc[m][n], 0, 0, 0);
        }
        __syncthreads();
    }

    // epilogue: cost = max(MARGIN - sqrt(max(imsq[i]+exsq[j]-2*dot,0)) - diag[i], 0)
    // C/D layout (HW-verified): col = lane&15, row = (lane>>4)*4 + reg
    float lsum = 0.f;
    int r0 = (lane >> 4) * 4;
    int cc = lane & 15;
    #pragma unroll
    for (int m = 0; m < 4; ++m) {
        int i0 = ibase + wr * 64 + m * 16 + r0;
        #pragma unroll
        for (int n = 0; n < 4; ++n) {
            int j = jbase + wc * 64 + n * 16 + cc;
            float esq = exsq[j];
            #pragma unroll
            for (int r = 0; r < 4; ++r) {
                int i = i0 + r;
                float d2 = imsq[i] + esq - 2.0f * acc[m][n][r];
                d2 = fmaxf(d2, 0.0f);
                float c = MARGIN - sqrtf(d2) - diag[i];
                lsum += fmaxf(c, 0.0f);
            }
        }
    }
    #pragma unroll
    for (int off = 32; off > 0; off >>= 1) lsum += __shfl_down(lsum, off);
    __shared__ float redbuf[4];
    if (lane == 0) redbuf[w] = lsum;
    __syncthreads();
    if (tid == 0) partials[bid] = redbuf[0] + redbuf[1] + redbuf[2] + redbuf[3];
}

// ---------------------------------------------------------------------------
// deterministic final reduce: 4096 partials -> mean
// ---------------------------------------------------------------------------
__global__ __launch_bounds__(256) void finalize_kernel(
    const float* __restrict__ partials, float* __restrict__ out) {
    float acc = 0.f;
    for (int t = threadIdx.x; t < 4096; t += 256) acc += partials[t];
    #pragma unroll
    for (int off = 32; off > 0; off >>= 1) acc += __shfl_down(acc, off);
    __shared__ float sred[4];
    int lane = threadIdx.x & 63, w = threadIdx.x >> 6;
    if (lane == 0) sred[w] = acc;
    __syncthreads();
    if (threadIdx.x == 0) {
        float total = sred[0] + sred[1] + sred[2] + sred[3];
        out[0] = total * (1.0f / (8192.0f * 8192.0f));  // exact pow2 scale
    }
}

extern "C" void kernel_launch(void* const* d_in, const int* in_sizes, int n_in,
                              void* d_out, int out_size, void* d_ws, size_t ws_size,
                              hipStream_t stream) {
    const float* im = (const float*)d_in[0];
    const float* s  = (const float*)d_in[1];
    const float* ex = (const float*)d_in[2];

    // workspace layout (~16.9 MB)
    char* ws = (char*)d_ws;
    ushort* Abf   = (ushort*)(ws);                       // 8 MB
    ushort* Bbf   = (ushort*)(ws + 8388608);             // 8 MB
    float* imsq   = (float*)(ws + 16777216);             // 32 KB
    float* exsq   = (float*)(ws + 16809984);             // 32 KB
    float* diag   = (float*)(ws + 16842752);             // 32 KB
    float* parts  = (float*)(ws + 16875520);             // 16 KB

    prep_kernel<<<2 * NROW, 256, 0, stream>>>(im, s, ex, Abf, Bbf, imsq, exsq, diag);
    gemm_cost_kernel<<<(NROW / BM) * (NROW / BN), 256, 0, stream>>>(Abf, Bbf, imsq, exsq, diag, parts);
    finalize_kernel<<<1, 256, 0, stream>>>(parts, (float*)d_out);
}

// Round 8
// 117.111 us; speedup vs baseline: 1.2111x; 1.2090x over previous
//
#include <hip/hip_runtime.h>
#include <hip/hip_bf16.h>

#define NROW 8192
#define DDIM 512
#define MARGIN 0.2f

typedef __bf16 bf16x8 __attribute__((ext_vector_type(8)));
typedef float f32x4 __attribute__((ext_vector_type(4)));

__device__ __forceinline__ void gload16(const void* g, void* l) {
    __builtin_amdgcn_global_load_lds(
        (const __attribute__((address_space(1))) void*)g,
        (__attribute__((address_space(3))) void*)l, 16, 0, 0);
}

#define BAR() __builtin_amdgcn_s_barrier()
#define LGKM0() asm volatile("s_waitcnt lgkmcnt(0)" ::: "memory")

// ---------------------------------------------------------------------------
// prep: blocks 0..N-1 handle im (convert + idat={||im||^2, MARGIN+||im-s||}),
//       N..2N-1 handle ex (convert + ||ex||^2)
// ---------------------------------------------------------------------------
__global__ __launch_bounds__(256) void prep_kernel(
    const float* __restrict__ im, const float* __restrict__ s,
    const float* __restrict__ ex,
    ushort* __restrict__ Abf, ushort* __restrict__ Bbf,
    float2* __restrict__ idat, float* __restrict__ exsq) {
    int b = blockIdx.x;
    bool isim = b < NROW;
    int row = isim ? b : b - NROW;
    const float* src = isim ? im : ex;
    ushort* dst = isim ? Abf : Bbf;
    int tid = threadIdx.x;

    float2 v = ((const float2*)(src + (size_t)row * DDIM))[tid];
    __hip_bfloat16 hx = __float2bfloat16(v.x);
    __hip_bfloat16 hy = __float2bfloat16(v.y);
    unsigned packed = (unsigned)*(const ushort*)&hx | ((unsigned)*(const ushort*)&hy << 16);
    ((unsigned*)(dst + (size_t)row * DDIM))[tid] = packed;

    float ssq = v.x * v.x + v.y * v.y;
    float dsq = 0.f;
    if (isim) {
        float2 sv = ((const float2*)(s + (size_t)row * DDIM))[tid];
        float dx = v.x - sv.x, dy = v.y - sv.y;
        dsq = dx * dx + dy * dy;
    }
    #pragma unroll
    for (int off = 32; off > 0; off >>= 1) {
        ssq += __shfl_down(ssq, off);
        dsq += __shfl_down(dsq, off);
    }
    __shared__ float sred[8];
    int lane = tid & 63, w = tid >> 6;
    if (lane == 0) { sred[w] = ssq; sred[4 + w] = dsq; }
    __syncthreads();
    if (tid == 0) {
        float S = sred[0] + sred[1] + sred[2] + sred[3];
        float Dd = sred[4] + sred[5] + sred[6] + sred[7];
        if (isim) idat[row] = make_float2(S, MARGIN + sqrtf(Dd));
        else      exsq[row] = S;
    }
}

// ---------------------------------------------------------------------------
// 256x256 8-phase GEMM + fused epilogue. 8 waves (2Mx4N), BK=64, dbuf LDS.
// LDS rows 128B with chunk16 swizzle: phys = logical ^ (row&7) (both sides).
// Half-tiles (16KB): id h = 4*ktile + q, q: 0=A-lo 1=A-hi 2=B-lo 3=B-hi.
// Prologue stages h=0..5, vmcnt(4). K-tile t phases stage h=4t+6..4t+9.
// Reads: ph0 = A m0-3 + B n0-1 (12), ph1 = A m4-7 (8), ph2 = B n2-3 (4),
// ph3 = 0. Boundary wait vmcnt(4) (t<6), vmcnt(0) (t==6).
// ---------------------------------------------------------------------------
__global__ __launch_bounds__(512) void gemm_cost_kernel(
    const ushort* __restrict__ Abf, const ushort* __restrict__ Bbf,
    const float2* __restrict__ idat, const float* __restrict__ exsq,
    float* __restrict__ partials) {
    __shared__ __align__(16) ushort sA[2][16384];  // 64 KB
    __shared__ __align__(16) ushort sB[2][16384];  // 64 KB
    __shared__ float redbuf[8];

    // XCD-aware bijective swizzle: nwg = 1024, %8 == 0
    int bid0 = blockIdx.x;
    int bid = (bid0 & 7) * 128 + (bid0 >> 3);
    int bi = bid >> 5, bj = bid & 31;
    int ibase = bi * 256, jbase = bj * 256;
    int tid = threadIdx.x, lane = tid & 63, w = tid >> 6;
    int wr = w >> 2, wc = w & 3;

    // staging per-thread constants: chunk c = tid (and +512), r=c>>3, pc=c&7
    int r = tid >> 3;            // 0..63 (second load: r+64)
    int pc = tid & 7;            // physical 16B chunk in row
    int lc = pc ^ (r & 7);       // logical chunk (source pre-swizzle)
    const ushort* aG = Abf + (size_t)(ibase + r) * DDIM + lc * 8;
    const ushort* bG = Bbf + (size_t)(jbase + r) * DDIM + lc * 8;
    ushort* aL = &sA[0][0] + r * 64 + pc * 8;
    ushort* bL = &sB[0][0] + r * 64 + pc * 8;

    auto STAGE = [&](int h) {
        if (h >= 32) return;
        int kt = h >> 2, q = h & 3;
        if (q < 2) {
            const ushort* g = aG + q * (128 * DDIM) + kt * 64;
            ushort* l = aL + (kt & 1) * 16384 + q * 8192;
            gload16(g, l);
            gload16(g + 64 * DDIM, l + 4096);
        } else {
            int qq = q - 2;
            const ushort* g = bG + qq * (128 * DDIM) + kt * 64;
            ushort* l = bL + (kt & 1) * 16384 + qq * 8192;
            gload16(g, l);
            gload16(g + 64 * DDIM, l + 4096);
        }
    };

    // ds_read per-thread constants (read-side swizzle: chunk ^= row&7 = lane&7)
    int l15 = lane & 15;
    int pc0 = (((lane >> 4) ^ (lane & 7)) * 8);  // ushort offset, ks=0
    int pc1 = pc0 ^ 32;                          // ks=1 (^4 chunks)
    int aoff = (wr * 128 + l15) * 64;
    int boff = (wc * 64 + l15) * 64;

    f32x4 acc[8][4] = {};

    // prologue: halves 0..5 (K0 complete + K1 A-halves)
    STAGE(0); STAGE(1); STAGE(2); STAGE(3); STAGE(4); STAGE(5);
    asm volatile("s_waitcnt vmcnt(4)" ::: "memory");
    BAR();

    #pragma unroll
    for (int t = 0; t < 8; ++t) {
        const ushort* pA = &sA[t & 1][0];
        const ushort* pB = &sB[t & 1][0];
        bf16x8 a0[4][2], a1[4][2], b0[2][2], b1[2][2];

        // ---- phase 0: read A m0-3 (8) + B n0-1 (4); stage 4t+6; MFMA Q(0,0)
        #pragma unroll
        for (int m = 0; m < 4; ++m) {
            a0[m][0] = *(const bf16x8*)(pA + aoff + m * 1024 + pc0);
            a0[m][1] = *(const bf16x8*)(pA + aoff + m * 1024 + pc1);
        }
        #pragma unroll
        for (int n = 0; n < 2; ++n) {
            b0[n][0] = *(const bf16x8*)(pB + boff + n * 1024 + pc0);
            b0[n][1] = *(const bf16x8*)(pB + boff + n * 1024 + pc1);
        }
        STAGE(4 * t + 6);
        BAR(); LGKM0();
        __builtin_amdgcn_s_setprio(1);
        #pragma unroll
        for (int m = 0; m < 4; ++m)
            #pragma unroll
            for (int n = 0; n < 2; ++n) {
                acc[m][n] = __builtin_amdgcn_mfma_f32_16x16x32_bf16(a0[m][0], b0[n][0], acc[m][n], 0, 0, 0);
                acc[m][n] = __builtin_amdgcn_mfma_f32_16x16x32_bf16(a0[m][1], b0[n][1], acc[m][n], 0, 0, 0);
            }
        __builtin_amdgcn_s_setprio(0);
        BAR();

        // ---- phase 1: read A m4-7 (8); stage 4t+7; MFMA Q(1,0)
        #pragma unroll
        for (int m = 0; m < 4; ++m) {
            a1[m][0] = *(const bf16x8*)(pA + aoff + (m + 4) * 1024 + pc0);
            a1[m][1] = *(const bf16x8*)(pA + aoff + (m + 4) * 1024 + pc1);
        }
        STAGE(4 * t + 7);
        BAR(); LGKM0();
        __builtin_amdgcn_s_setprio(1);
        #pragma unroll
        for (int m = 0; m < 4; ++m)
            #pragma unroll
            for (int n = 0; n < 2; ++n) {
                acc[m + 4][n] = __builtin_amdgcn_mfma_f32_16x16x32_bf16(a1[m][0], b0[n][0], acc[m + 4][n], 0, 0, 0);
                acc[m + 4][n] = __builtin_amdgcn_mfma_f32_16x16x32_bf16(a1[m][1], b0[n][1], acc[m + 4][n], 0, 0, 0);
            }
        __builtin_amdgcn_s_setprio(0);
        BAR();

        // ---- phase 2: read B n2-3 (4); stage 4t+8; MFMA Q(0,1)
        #pragma unroll
        for (int n = 0; n < 2; ++n) {
            b1[n][0] = *(const bf16x8*)(pB + boff + (n + 2) * 1024 + pc0);
            b1[n][1] = *(const bf16x8*)(pB + boff + (n + 2) * 1024 + pc1);
        }
        STAGE(4 * t + 8);
        BAR(); LGKM0();
        __builtin_amdgcn_s_setprio(1);
        #pragma unroll
        for (int m = 0; m < 4; ++m)
            #pragma unroll
            for (int n = 0; n < 2; ++n) {
                acc[m][n + 2] = __builtin_amdgcn_mfma_f32_16x16x32_bf16(a0[m][0], b1[n][0], acc[m][n + 2], 0, 0, 0);
                acc[m][n + 2] = __builtin_amdgcn_mfma_f32_16x16x32_bf16(a0[m][1], b1[n][1], acc[m][n + 2], 0, 0, 0);
            }
        __builtin_amdgcn_s_setprio(0);
        BAR();

        // ---- phase 3: stage 4t+9; MFMA Q(1,1); K-tile boundary wait
        STAGE(4 * t + 9);
        BAR(); LGKM0();
        __builtin_amdgcn_s_setprio(1);
        #pragma unroll
        for (int m = 0; m < 4; ++m)
            #pragma unroll
            for (int n = 0; n < 2; ++n) {
                acc[m + 4][n + 2] = __builtin_amdgcn_mfma_f32_16x16x32_bf16(a1[m][0], b1[n][0], acc[m + 4][n + 2], 0, 0, 0);
                acc[m + 4][n + 2] = __builtin_amdgcn_mfma_f32_16x16x32_bf16(a1[m][1], b1[n][1], acc[m + 4][n + 2], 0, 0, 0);
            }
        __builtin_amdgcn_s_setprio(0);
        if (t < 6)       asm volatile("s_waitcnt vmcnt(4)" ::: "memory");
        else if (t == 6) asm volatile("s_waitcnt vmcnt(0)" ::: "memory");
        BAR();
    }

    // epilogue: cost = max(idat.y - sqrt(max(idat.x + exsq[j] - 2*dot, 0)), 0)
    // C/D layout: col = lane&15, row = (lane>>4)*4 + reg
    float jt[4];
    #pragma unroll
    for (int n = 0; n < 4; ++n) jt[n] = exsq[jbase + wc * 64 + n * 16 + l15];
    int r0 = (lane >> 4) * 4;
    float lsum = 0.f;
    #pragma unroll
    for (int m = 0; m < 8; ++m) {
        #pragma unroll
        for (int rg = 0; rg < 4; ++rg) {
            int i = ibase + wr * 128 + m * 16 + r0 + rg;
            float2 id = idat[i];
            #pragma unroll
            for (int n = 0; n < 4; ++n) {
                float d2 = fmaxf(id.x + jt[n] - 2.0f * acc[m][n][rg], 0.0f);
                lsum += fmaxf(id.y - sqrtf(d2), 0.0f);
            }
        }
    }
    #pragma unroll
    for (int off = 32; off > 0; off >>= 1) lsum += __shfl_down(lsum, off);
    if (lane == 0) redbuf[w] = lsum;
    __syncthreads();
    if (tid == 0) {
        float tot = 0.f;
        #pragma unroll
        for (int q = 0; q < 8; ++q) tot += redbuf[q];
        partials[bid] = tot;
    }
}

// ---------------------------------------------------------------------------
// deterministic final reduce: 1024 partials -> mean
// ---------------------------------------------------------------------------
__global__ __launch_bounds__(256) void finalize_kernel(
    const float* __restrict__ partials, float* __restrict__ out) {
    float acc = 0.f;
    for (int t = threadIdx.x; t < 1024; t += 256) acc += partials[t];
    #pragma unroll
    for (int off = 32; off > 0; off >>= 1) acc += __shfl_down(acc, off);
    __shared__ float sred[4];
    int lane = threadIdx.x & 63, w = threadIdx.x >> 6;
    if (lane == 0) sred[w] = acc;
    __syncthreads();
    if (threadIdx.x == 0) {
        float total = sred[0] + sred[1] + sred[2] + sred[3];
        out[0] = total * (1.0f / (8192.0f * 8192.0f));  // exact pow2 scale
    }
}

extern "C" void kernel_launch(void* const* d_in, const int* in_sizes, int n_in,
                              void* d_out, int out_size, void* d_ws, size_t ws_size,
                              hipStream_t stream) {
    const float* im = (const float*)d_in[0];
    const float* s  = (const float*)d_in[1];
    const float* ex = (const float*)d_in[2];

    // workspace layout (~16.2 MB)
    char* ws = (char*)d_ws;
    ushort* Abf   = (ushort*)(ws);                       // 8 MB
    ushort* Bbf   = (ushort*)(ws + 8388608);             // 8 MB
    float2* idat  = (float2*)(ws + 16777216);            // 64 KB
    float*  exsq  = (float*)(ws + 16842752);             // 32 KB
    float*  parts = (float*)(ws + 16875520);             // 4 KB

    prep_kernel<<<2 * NROW, 256, 0, stream>>>(im, s, ex, Abf, Bbf, idat, exsq);
    gemm_cost_kernel<<<(NROW / 256) * (NROW / 256), 512, 0, stream>>>(Abf, Bbf, idat, exsq, parts);
    finalize_kernel<<<1, 256, 0, stream>>>(parts, (float*)d_out);
}

// Round 9
// 109.221 us; speedup vs baseline: 1.2986x; 1.0722x over previous
//
#include <hip/hip_runtime.h>
#include <hip/hip_bf16.h>

#define NROW 8192
#define DDIM 512
#define MARGIN 0.2f

typedef __bf16 bf16x8 __attribute__((ext_vector_type(8)));
typedef float f32x4 __attribute__((ext_vector_type(4)));

__device__ __forceinline__ void gload16(const void* g, void* l) {
    __builtin_amdgcn_global_load_lds(
        (const __attribute__((address_space(1))) void*)g,
        (__attribute__((address_space(3))) void*)l, 16, 0, 0);
}

#define BAR() __builtin_amdgcn_s_barrier()
#define LGKM0() asm volatile("s_waitcnt lgkmcnt(0)" ::: "memory")

// ---------------------------------------------------------------------------
// prep: blocks 0..N-1 handle im (convert + idat={||im||^2, MARGIN+||im-s||}),
//       N..2N-1 handle ex (convert + ||ex||^2)
// ---------------------------------------------------------------------------
__global__ __launch_bounds__(256) void prep_kernel(
    const float* __restrict__ im, const float* __restrict__ s,
    const float* __restrict__ ex,
    ushort* __restrict__ Abf, ushort* __restrict__ Bbf,
    float2* __restrict__ idat, float* __restrict__ exsq) {
    int b = blockIdx.x;
    bool isim = b < NROW;
    int row = isim ? b : b - NROW;
    const float* src = isim ? im : ex;
    ushort* dst = isim ? Abf : Bbf;
    int tid = threadIdx.x;

    float2 v = ((const float2*)(src + (size_t)row * DDIM))[tid];
    __hip_bfloat16 hx = __float2bfloat16(v.x);
    __hip_bfloat16 hy = __float2bfloat16(v.y);
    unsigned packed = (unsigned)*(const ushort*)&hx | ((unsigned)*(const ushort*)&hy << 16);
    ((unsigned*)(dst + (size_t)row * DDIM))[tid] = packed;

    float ssq = v.x * v.x + v.y * v.y;
    float dsq = 0.f;
    if (isim) {
        float2 sv = ((const float2*)(s + (size_t)row * DDIM))[tid];
        float dx = v.x - sv.x, dy = v.y - sv.y;
        dsq = dx * dx + dy * dy;
    }
    #pragma unroll
    for (int off = 32; off > 0; off >>= 1) {
        ssq += __shfl_down(ssq, off);
        dsq += __shfl_down(dsq, off);
    }
    __shared__ float sred[8];
    int lane = tid & 63, w = tid >> 6;
    if (lane == 0) { sred[w] = ssq; sred[4 + w] = dsq; }
    __syncthreads();
    if (tid == 0) {
        float S = sred[0] + sred[1] + sred[2] + sred[3];
        float Dd = sred[4] + sred[5] + sred[6] + sred[7];
        if (isim) idat[row] = make_float2(S, MARGIN + sqrtf(Dd));
        else      exsq[row] = S;
    }
}

// ---------------------------------------------------------------------------
// 256x256 8-phase GEMM + fused epilogue. 8 waves (2Mx4N), BK=64, dbuf LDS.
// LDS rows 128B with chunk16 swizzle: phys = logical ^ (row&7) (both sides).
// Half-tiles (16KB): id h = 4*ktile + q, q: 0=A-lo 1=A-hi 2=B-lo 3=B-hi.
// Staging: prologue stages tiles 0,1 (16 loads), vmcnt(8) seals tile 0.
// Iter t stages tile t+2: A-halves at ph2 (A-reads of buf t&1 done by
// ph1-end), B-halves at ph3 (B-reads done by ph2-end). Boundary wait:
// vmcnt(8) (t<6) seals tile t+1, vmcnt(0) at t==6. ~5-6 phase staging lead.
// Block map: XCD c = bid0&7 owns bi in [4c,4c+4); within, 4x8 windows so the
// ~32 co-resident blocks/XCD touch 1MB A + 2MB B < 4MB L2 (round-8 profile
// showed 136MB HBM fetch = L2 thrash from row-of-tiles co-residency).
// ---------------------------------------------------------------------------
__global__ __launch_bounds__(512) void gemm_cost_kernel(
    const ushort* __restrict__ Abf, const ushort* __restrict__ Bbf,
    const float2* __restrict__ idat, const float* __restrict__ exsq,
    float* __restrict__ partials) {
    __shared__ __align__(16) ushort sA[2][16384];  // 64 KB
    __shared__ __align__(16) ushort sB[2][16384];  // 64 KB
    __shared__ float redbuf[8];

    // XCD-aware square-window mapping (bijective over 32x32 tiles)
    int bid0 = blockIdx.x;
    int c = bid0 & 7;            // assumed XCD id
    int sq = bid0 >> 3;          // 0..127 sequence within XCD
    int bi = c * 4 + (sq & 3);
    int bj = (sq >> 5) * 8 + ((sq >> 2) & 7);
    int bid = bi * 32 + bj;      // for partials indexing (bijective)
    int ibase = bi * 256, jbase = bj * 256;
    int tid = threadIdx.x, lane = tid & 63, w = tid >> 6;
    int wr = w >> 2, wc = w & 3;

    // staging per-thread constants: chunk c = tid (and +512), r=c>>3, pc=c&7
    int r = tid >> 3;            // 0..63 (second load: r+64)
    int pc = tid & 7;            // physical 16B chunk in row
    int lc = pc ^ (r & 7);       // logical chunk (source pre-swizzle)
    const ushort* aG = Abf + (size_t)(ibase + r) * DDIM + lc * 8;
    const ushort* bG = Bbf + (size_t)(jbase + r) * DDIM + lc * 8;
    ushort* aL = &sA[0][0] + r * 64 + pc * 8;
    ushort* bL = &sB[0][0] + r * 64 + pc * 8;

    auto STAGE = [&](int h) {
        if (h >= 32) return;
        int kt = h >> 2, q = h & 3;
        if (q < 2) {
            const ushort* g = aG + q * (128 * DDIM) + kt * 64;
            ushort* l = aL + (kt & 1) * 16384 + q * 8192;
            gload16(g, l);
            gload16(g + 64 * DDIM, l + 4096);
        } else {
            int qq = q - 2;
            const ushort* g = bG + qq * (128 * DDIM) + kt * 64;
            ushort* l = bL + (kt & 1) * 16384 + qq * 8192;
            gload16(g, l);
            gload16(g + 64 * DDIM, l + 4096);
        }
    };

    // ds_read per-thread constants (read-side swizzle: chunk ^= row&7 = lane&7)
    int l15 = lane & 15;
    int pc0 = (((lane >> 4) ^ (lane & 7)) * 8);  // ushort offset, ks=0
    int pc1 = pc0 ^ 32;                          // ks=1 (^4 chunks)
    int aoff = (wr * 128 + l15) * 64;
    int boff = (wc * 64 + l15) * 64;

    f32x4 acc[8][4] = {};

    // prologue: tiles 0 and 1 fully staged (16 loads); vmcnt(8) seals tile 0
    STAGE(0); STAGE(1); STAGE(2); STAGE(3);
    STAGE(4); STAGE(5); STAGE(6); STAGE(7);
    asm volatile("s_waitcnt vmcnt(8)" ::: "memory");
    BAR();

    #pragma unroll
    for (int t = 0; t < 8; ++t) {
        const ushort* pA = &sA[t & 1][0];
        const ushort* pB = &sB[t & 1][0];
        bf16x8 a0[4][2], a1[4][2], b0[2][2], b1[2][2];

        // ---- phase 0: read A m0-3 (8) + B n0-1 (4); MFMA Q(0,0)
        #pragma unroll
        for (int m = 0; m < 4; ++m) {
            a0[m][0] = *(const bf16x8*)(pA + aoff + m * 1024 + pc0);
            a0[m][1] = *(const bf16x8*)(pA + aoff + m * 1024 + pc1);
        }
        #pragma unroll
        for (int n = 0; n < 2; ++n) {
            b0[n][0] = *(const bf16x8*)(pB + boff + n * 1024 + pc0);
            b0[n][1] = *(const bf16x8*)(pB + boff + n * 1024 + pc1);
        }
        BAR(); LGKM0();
        __builtin_amdgcn_s_setprio(1);
        #pragma unroll
        for (int m = 0; m < 4; ++m)
            #pragma unroll
            for (int n = 0; n < 2; ++n) {
                acc[m][n] = __builtin_amdgcn_mfma_f32_16x16x32_bf16(a0[m][0], b0[n][0], acc[m][n], 0, 0, 0);
                acc[m][n] = __builtin_amdgcn_mfma_f32_16x16x32_bf16(a0[m][1], b0[n][1], acc[m][n], 0, 0, 0);
            }
        __builtin_amdgcn_s_setprio(0);
        BAR();

        // ---- phase 1: read A m4-7 (8); MFMA Q(1,0)
        #pragma unroll
        for (int m = 0; m < 4; ++m) {
            a1[m][0] = *(const bf16x8*)(pA + aoff + (m + 4) * 1024 + pc0);
            a1[m][1] = *(const bf16x8*)(pA + aoff + (m + 4) * 1024 + pc1);
        }
        BAR(); LGKM0();
        __builtin_amdgcn_s_setprio(1);
        #pragma unroll
        for (int m = 0; m < 4; ++m)
            #pragma unroll
            for (int n = 0; n < 2; ++n) {
                acc[m + 4][n] = __builtin_amdgcn_mfma_f32_16x16x32_bf16(a1[m][0], b0[n][0], acc[m + 4][n], 0, 0, 0);
                acc[m + 4][n] = __builtin_amdgcn_mfma_f32_16x16x32_bf16(a1[m][1], b0[n][1], acc[m + 4][n], 0, 0, 0);
            }
        __builtin_amdgcn_s_setprio(0);
        BAR();

        // ---- phase 2: read B n2-3 (4); stage A-halves of tile t+2; MFMA Q(0,1)
        #pragma unroll
        for (int n = 0; n < 2; ++n) {
            b1[n][0] = *(const bf16x8*)(pB + boff + (n + 2) * 1024 + pc0);
            b1[n][1] = *(const bf16x8*)(pB + boff + (n + 2) * 1024 + pc1);
        }
        STAGE(4 * (t + 2) + 0);
        STAGE(4 * (t + 2) + 1);
        BAR(); LGKM0();
        __builtin_amdgcn_s_setprio(1);
        #pragma unroll
        for (int m = 0; m < 4; ++m)
            #pragma unroll
            for (int n = 0; n < 2; ++n) {
                acc[m][n + 2] = __builtin_amdgcn_mfma_f32_16x16x32_bf16(a0[m][0], b1[n][0], acc[m][n + 2], 0, 0, 0);
                acc[m][n + 2] = __builtin_amdgcn_mfma_f32_16x16x32_bf16(a0[m][1], b1[n][1], acc[m][n + 2], 0, 0, 0);
            }
        __builtin_amdgcn_s_setprio(0);
        BAR();

        // ---- phase 3: stage B-halves of tile t+2; MFMA Q(1,1); boundary wait
        STAGE(4 * (t + 2) + 2);
        STAGE(4 * (t + 2) + 3);
        BAR();
        __builtin_amdgcn_s_setprio(1);
        #pragma unroll
        for (int m = 0; m < 4; ++m)
            #pragma unroll
            for (int n = 0; n < 2; ++n) {
                acc[m + 4][n + 2] = __builtin_amdgcn_mfma_f32_16x16x32_bf16(a1[m][0], b1[n][0], acc[m + 4][n + 2], 0, 0, 0);
                acc[m + 4][n + 2] = __builtin_amdgcn_mfma_f32_16x16x32_bf16(a1[m][1], b1[n][1], acc[m + 4][n + 2], 0, 0, 0);
            }
        __builtin_amdgcn_s_setprio(0);
        if (t < 6)       asm volatile("s_waitcnt vmcnt(8)" ::: "memory");
        else if (t == 6) asm volatile("s_waitcnt vmcnt(0)" ::: "memory");
        BAR();
    }

    // epilogue: cost = max(idat.y - sqrt(max(idat.x + exsq[j] - 2*dot, 0)), 0)
    // C/D layout: col = lane&15, row = (lane>>4)*4 + reg
    float jt[4];
    #pragma unroll
    for (int n = 0; n < 4; ++n) jt[n] = exsq[jbase + wc * 64 + n * 16 + l15];
    int r0 = (lane >> 4) * 4;
    float lsum = 0.f;
    #pragma unroll
    for (int m = 0; m < 8; ++m) {
        #pragma unroll
        for (int rg = 0; rg < 4; ++rg) {
            int i = ibase + wr * 128 + m * 16 + r0 + rg;
            float2 id = idat[i];
            #pragma unroll
            for (int n = 0; n < 4; ++n) {
                float d2 = fmaxf(id.x + jt[n] - 2.0f * acc[m][n][rg], 0.0f);
                lsum += fmaxf(id.y - sqrtf(d2), 0.0f);
            }
        }
    }
    #pragma unroll
    for (int off = 32; off > 0; off >>= 1) lsum += __shfl_down(lsum, off);
    if (lane == 0) redbuf[w] = lsum;
    __syncthreads();
    if (tid == 0) {
        float tot = 0.f;
        #pragma unroll
        for (int q = 0; q < 8; ++q) tot += redbuf[q];
        partials[bid] = tot;
    }
}

// ---------------------------------------------------------------------------
// deterministic final reduce: 1024 partials -> mean
// ---------------------------------------------------------------------------
__global__ __launch_bounds__(256) void finalize_kernel(
    const float* __restrict__ partials, float* __restrict__ out) {
    float acc = 0.f;
    for (int t = threadIdx.x; t < 1024; t += 256) acc += partials[t];
    #pragma unroll
    for (int off = 32; off > 0; off >>= 1) acc += __shfl_down(acc, off);
    __shared__ float sred[4];
    int lane = threadIdx.x & 63, w = threadIdx.x >> 6;
    if (lane == 0) sred[w] = acc;
    __syncthreads();
    if (threadIdx.x == 0) {
        float total = sred[0] + sred[1] + sred[2] + sred[3];
        out[0] = total * (1.0f / (8192.0f * 8192.0f));  // exact pow2 scale
    }
}

extern "C" void kernel_launch(void* const* d_in, const int* in_sizes, int n_in,
                              void* d_out, int out_size, void* d_ws, size_t ws_size,
                              hipStream_t stream) {
    const float* im = (const float*)d_in[0];
    const float* s  = (const float*)d_in[1];
    const float* ex = (const float*)d_in[2];

    // workspace layout (~16.2 MB)
    char* ws = (char*)d_ws;
    ushort* Abf   = (ushort*)(ws);                       // 8 MB
    ushort* Bbf   = (ushort*)(ws + 8388608);             // 8 MB
    float2* idat  = (float2*)(ws + 16777216);            // 64 KB
    float*  exsq  = (float*)(ws + 16842752);             // 32 KB
    float*  parts = (float*)(ws + 16875520);             // 4 KB

    prep_kernel<<<2 * NROW, 256, 0, stream>>>(im, s, ex, Abf, Bbf, idat, exsq);
    gemm_cost_kernel<<<(NROW / 256) * (NROW / 256), 512, 0, stream>>>(Abf, Bbf, idat, exsq, parts);
    finalize_kernel<<<1, 256, 0, stream>>>(parts, (float*)d_out);
}